// Round 4
// baseline (196.888 us; speedup 1.0000x reference)
//
#include <hip/hip_runtime.h>
#include <hip/hip_bf16.h>

#define CCH 256
#define HEADS 4

typedef float f4 __attribute__((ext_vector_type(4)));

// ---------------- Kernel 1: pool rgb + dep (NT) + x_ful (temporal) ----------------
// wave-per-row: 64 lanes x 16 float4 = 4096 floats. 24576 row-waves / 4 = 6144 blocks.
// Order: rgb rows, dep rows, then x_ful rows (latest -> freshest in L3 for apply).
__global__ __launch_bounds__(256) void pool_kernel(
    const float* __restrict__ rgb, const float* __restrict__ dep,
    const float* __restrict__ xf, float* __restrict__ nodes /* [32][4][256] */)
{
    const int rw   = blockIdx.x * 4 + (threadIdx.x >> 6);  // 0..24575
    const int lane = threadIdx.x & 63;
    const int tensor = rw >> 13;              // 0 = rgb, 1 = dep, 2 = x_ful
    const int row    = rw & 8191;             // b*256 + c
    const float* base = (tensor == 0) ? rgb : (tensor == 1) ? dep : xf;
    const f4* src = (const f4*)(base + (size_t)row * 4096);

    f4 acc = {0.f, 0.f, 0.f, 0.f};
    if (tensor < 2) {                         // nontemporal: don't pollute L3
        f4 v[8];
#pragma unroll
        for (int j = 0; j < 8; ++j) v[j] = __builtin_nontemporal_load(src + lane + 64 * j);
#pragma unroll
        for (int j = 0; j < 8; ++j) acc += v[j];
#pragma unroll
        for (int j = 0; j < 8; ++j) v[j] = __builtin_nontemporal_load(src + lane + 64 * (8 + j));
#pragma unroll
        for (int j = 0; j < 8; ++j) acc += v[j];
    } else {                                  // temporal: keep x_ful in L3
        f4 v[8];
#pragma unroll
        for (int j = 0; j < 8; ++j) v[j] = src[lane + 64 * j];
#pragma unroll
        for (int j = 0; j < 8; ++j) acc += v[j];
#pragma unroll
        for (int j = 0; j < 8; ++j) v[j] = src[lane + 64 * (8 + j)];
#pragma unroll
        for (int j = 0; j < 8; ++j) acc += v[j];
    }

    float s = acc.x + acc.y + acc.z + acc.w;
#pragma unroll
    for (int off = 32; off; off >>= 1) s += __shfl_down(s, off, 64);
    if (lane == 0) {
        const int b = row >> 8, c = row & 255;
        const int nrow = (tensor == 2) ? 1 : (2 + tensor);
        nodes[(size_t)b * 1024 + nrow * CCH + c] = s * (1.f / 4096.f);
    }
}

// ---------------- Kernel 2: 2x (GATConv + residual + LN + ReLU), output gate ----------------
// grid: 32 blocks (batch), 512 threads: c = t&255, kh = t>>8 splits K in half.
// acc[4][4] (head j x node n) stays in registers; halves combine via LDS once.
__global__ __launch_bounds__(512) void gat_kernel(
    const float* __restrict__ nodes, const float* __restrict__ tok,
    float* __restrict__ scale,
    const float* __restrict__ W0, const float* __restrict__ as0,
    const float* __restrict__ ad0, const float* __restrict__ b0,
    const float* __restrict__ g0, const float* __restrict__ be0,
    const float* __restrict__ W1, const float* __restrict__ as1,
    const float* __restrict__ ad1, const float* __restrict__ b1,
    const float* __restrict__ g1, const float* __restrict__ be1)
{
    const int t = threadIdx.x;          // 0..511
    const int b = blockIdx.x;
    const int c = t & 255, kh = t >> 8;
    const int lane = t & 63, wv = t >> 6;   // wv 0..7

    __shared__ float gl[4][CCH];            // node features (layer input)
    __shared__ float xpart[4][4][CCH];      // half-1 GEMM partials [j][n][c]
    __shared__ float redl[4][32];           // per-wave logits partials (waves 0-3)
    __shared__ float esed[32];              // es[n*4+h], ed at +16
    __shared__ float alpha_s[4][4][4];      // [dst][head][src-slot]
    __shared__ float red2[4][8];            // per-wave LN partials
    __shared__ float mu_s[4], rstd_s[4];

    if (t < 256) {
        gl[0][c] = tok[c];
        gl[1][c] = nodes[(size_t)b * 1024 + 256 + c];
        gl[2][c] = nodes[(size_t)b * 1024 + 512 + c];
        gl[3][c] = nodes[(size_t)b * 1024 + 768 + c];
    }
    __syncthreads();

    for (int layer = 0; layer < 2; ++layer) {
        const float* W  = layer ? W1  : W0;
        const float* As = layer ? as1 : as0;
        const float* Ad = layer ? ad1 : ad0;
        const float* Bi = layer ? b1  : b0;
        const float* Ga = layer ? g1  : g0;
        const float* Be = layer ? be1 : be0;

        // ---- xp = x @ W : this thread's K-half, 8-deep register staging
        float acc[4][4];
#pragma unroll
        for (int j = 0; j < 4; ++j)
#pragma unroll
            for (int n = 0; n < 4; ++n) acc[j][n] = 0.f;

        const float* Wp = W + c;
        const int kbase = kh * 128;
        for (int k0 = 0; k0 < 128; k0 += 8) {
            float wr[8][4];
#pragma unroll
            for (int u = 0; u < 8; ++u)
#pragma unroll
                for (int j = 0; j < 4; ++j)
                    wr[u][j] = Wp[(size_t)(kbase + k0 + u) * 1024 + j * 256];
#pragma unroll
            for (int u = 0; u < 8; ++u) {
                const int k = kbase + k0 + u;
                float g0v = gl[0][k], g1v = gl[1][k];
                float g2v = gl[2][k], g3v = gl[3][k];
#pragma unroll
                for (int j = 0; j < 4; ++j) {
                    float w = wr[u][j];
                    acc[j][0] += g0v * w;
                    acc[j][1] += g1v * w;
                    acc[j][2] += g2v * w;
                    acc[j][3] += g3v * w;
                }
            }
        }
        if (kh == 1) {
#pragma unroll
            for (int j = 0; j < 4; ++j)
#pragma unroll
                for (int n = 0; n < 4; ++n) xpart[j][n][c] = acc[j][n];
        }
        __syncthreads();

        float gv[4];
        if (kh == 0) {
#pragma unroll
            for (int j = 0; j < 4; ++j)
#pragma unroll
                for (int n = 0; n < 4; ++n) acc[j][n] += xpart[j][n][c];

            // ---- attention logits: 32 simultaneous shuffle-reductions over c
            float asr[4], adr[4];
#pragma unroll
            for (int j = 0; j < 4; ++j) { asr[j] = As[j * 256 + c]; adr[j] = Ad[j * 256 + c]; }
            float rv[32];
#pragma unroll
            for (int n = 0; n < 4; ++n)
#pragma unroll
                for (int j = 0; j < 4; ++j) {
                    rv[n * 4 + j]      = acc[j][n] * asr[j];
                    rv[16 + n * 4 + j] = acc[j][n] * adr[j];
                }
#pragma unroll
            for (int i = 0; i < 32; ++i)
#pragma unroll
                for (int off = 32; off; off >>= 1)
                    rv[i] += __shfl_down(rv[i], off, 64);
            if (lane == 0) {
#pragma unroll
                for (int i = 0; i < 32; ++i) redl[wv][i] = rv[i];
            }
        }
        __syncthreads();
        if (t < 32) esed[t] = redl[0][t] + redl[1][t] + redl[2][t] + redl[3][t];
        __syncthreads();

        // ---- per-destination segment softmax (16 threads: d*4+h)
        if (t < 16) {
            const int d = t >> 2, hh = t & 3;
            const int cnt[4]     = {4, 3, 3, 3};
            const int srcs[4][4] = {{1,2,3,0},{2,3,1,0},{1,3,2,0},{1,2,3,0}};
            float v[4];
            float m = -1e30f;
            const int n = cnt[d];
            for (int s = 0; s < n; ++s) {
                float e = esed[srcs[d][s] * 4 + hh] + esed[16 + d * 4 + hh];
                e = (e >= 0.f) ? e : 0.2f * e;         // leaky_relu 0.2
                v[s] = e; m = fmaxf(m, e);
            }
            float den = 0.f;
            for (int s = 0; s < n; ++s) { v[s] = expf(v[s] - m); den += v[s]; }
            float inv = 1.f / den;
            for (int s = 0; s < n; ++s) alpha_s[d][hh][s] = v[s] * inv;
            for (int s = n; s < 4; ++s) alpha_s[d][hh][s] = 0.f;
        }
        __syncthreads();

        if (kh == 0) {
            // ---- aggregate + head mean + bias + residual (registers)
            const int srcs2[4][4] = {{1,2,3,0},{2,3,1,0},{1,3,2,0},{1,2,3,0}};
            float bi = Bi[c];
#pragma unroll
            for (int d = 0; d < 4; ++d) {
                float sum = 0.f;
#pragma unroll
                for (int j = 0; j < 4; ++j) {
                    float mj = 0.f;
#pragma unroll
                    for (int s = 0; s < 4; ++s)
                        mj += alpha_s[d][j][s] * acc[j][srcs2[d][s]];
                    sum += mj;
                }
                gv[d] = 0.25f * sum + bi + gl[d][c];
            }

            // ---- LayerNorm: 8 simultaneous shuffle-reductions
            float rv2[8];
#pragma unroll
            for (int d = 0; d < 4; ++d) { rv2[d * 2] = gv[d]; rv2[d * 2 + 1] = gv[d] * gv[d]; }
#pragma unroll
            for (int i = 0; i < 8; ++i)
#pragma unroll
                for (int off = 32; off; off >>= 1)
                    rv2[i] += __shfl_down(rv2[i], off, 64);
            if (lane == 0) {
#pragma unroll
                for (int i = 0; i < 8; ++i) red2[wv][i] = rv2[i];
            }
        }
        __syncthreads();
        if (t < 4) {
            float s = red2[0][t*2]   + red2[1][t*2]   + red2[2][t*2]   + red2[3][t*2];
            float q = red2[0][t*2+1] + red2[1][t*2+1] + red2[2][t*2+1] + red2[3][t*2+1];
            float mu  = s * (1.f / 256.f);
            float var = q * (1.f / 256.f) - mu * mu;
            mu_s[t]   = mu;
            rstd_s[t] = rsqrtf(var + 1e-5f);
        }
        __syncthreads();
        if (kh == 0) {
            float ga = Ga[c], be = Be[c];
#pragma unroll
            for (int d = 0; d < 4; ++d) {
                float y = (gv[d] - mu_s[d]) * rstd_s[d] * ga + be;
                gl[d][c] = fmaxf(y, 0.f);
            }
        }
        __syncthreads();
    }

    // ---- output gate from token node: scale = 1 + sigmoid(g[b,0,c])
    if (t < 256) {
        float x = gl[0][c];
        scale[(size_t)b * CCH + c] = 1.f + 1.f / (1.f + expf(-x));
    }
}

// ---------------- Kernel 3: out = x_ful * (1 + sigmoid), nontemporal store ----------------
__global__ __launch_bounds__(256) void apply_kernel(
    const float* __restrict__ xf, const float* __restrict__ scale,
    float* __restrict__ out, int total4)
{
    int idx = blockIdx.x * 256 + threadIdx.x;
    const int stride = gridDim.x * 256;
    const f4* in4 = (const f4*)xf;
    f4* out4 = (f4*)out;
    for (; idx < total4; idx += stride) {
        f4 v = in4[idx];
        const float s = scale[idx >> 10];          // 1024 float4 per (b,c) row
        f4 o = v * s;
        __builtin_nontemporal_store(o, out4 + idx);
    }
}

extern "C" void kernel_launch(void* const* d_in, const int* in_sizes, int n_in,
                              void* d_out, int out_size, void* d_ws, size_t ws_size,
                              hipStream_t stream) {
    const float* x_ful = (const float*)d_in[0];
    const float* rgb   = (const float*)d_in[1];
    const float* dep   = (const float*)d_in[2];
    const float* tok   = (const float*)d_in[3];
    const float* W0  = (const float*)d_in[4];
    const float* as0 = (const float*)d_in[5];
    const float* ad0 = (const float*)d_in[6];
    const float* b0  = (const float*)d_in[7];
    const float* g0  = (const float*)d_in[8];
    const float* be0 = (const float*)d_in[9];
    const float* W1  = (const float*)d_in[10];
    const float* as1 = (const float*)d_in[11];
    const float* ad1 = (const float*)d_in[12];
    const float* b1  = (const float*)d_in[13];
    const float* g1  = (const float*)d_in[14];
    const float* be1 = (const float*)d_in[15];

    float* nodes = (float*)d_ws;                          // [32][4][256] = 128 KB
    float* scale = (float*)((char*)d_ws + 32 * 4 * CCH * sizeof(float)); // [32][256]
    float* out   = (float*)d_out;

    pool_kernel<<<6144, 256, 0, stream>>>(rgb, dep, x_ful, nodes);
    gat_kernel<<<32, 512, 0, stream>>>(nodes, tok, scale,
                                       W0, as0, ad0, b0, g0, be0,
                                       W1, as1, ad1, b1, g1, be1);
    const int total4 = 32 * CCH * 64 * 64 / 4;            // 8,388,608 float4
    apply_kernel<<<2048, 256, 0, stream>>>(x_ful, scale, out, total4);
}

// Round 5
// 168.991 us; speedup vs baseline: 1.1651x; 1.1651x over previous
//
#include <hip/hip_runtime.h>
#include <hip/hip_bf16.h>

#define CCH 256
#define HEADS 4

typedef float f4 __attribute__((ext_vector_type(4)));

// ---------------- Kernel 1a: pool rgb + dep (nontemporal) ----------------
// wave-per-row: 64 lanes x 16 float4 = 4096 floats; 16-deep register burst.
// launch_bounds(256,2): allow up to 256 VGPR so all 16 loads stay in flight.
__global__ __launch_bounds__(256, 2) void poolA_kernel(
    const float* __restrict__ rgb, const float* __restrict__ dep,
    float* __restrict__ nodes /* [32][4][256] */)
{
    const int rw   = blockIdx.x * 4 + (threadIdx.x >> 6);  // 0..16383
    const int lane = threadIdx.x & 63;
    const int tensor = rw >> 13;              // 0 = rgb, 1 = dep
    const int row    = rw & 8191;             // b*256 + c
    const f4* src = (const f4*)((tensor ? dep : rgb) + (size_t)row * 4096);

    f4 v[16];
#pragma unroll
    for (int j = 0; j < 16; ++j) v[j] = __builtin_nontemporal_load(src + lane + 64 * j);
    f4 a0 = v[0] + v[1], a1 = v[2] + v[3], a2 = v[4] + v[5], a3 = v[6] + v[7];
    f4 a4 = v[8] + v[9], a5 = v[10] + v[11], a6 = v[12] + v[13], a7 = v[14] + v[15];
    f4 acc = ((a0 + a1) + (a2 + a3)) + ((a4 + a5) + (a6 + a7));

    float s = acc.x + acc.y + acc.z + acc.w;
#pragma unroll
    for (int off = 32; off; off >>= 1) s += __shfl_down(s, off, 64);
    if (lane == 0) {
        const int b = row >> 8, c = row & 255;
        nodes[(size_t)b * 1024 + (2 + tensor) * CCH + c] = s * (1.f / 4096.f);
    }
}

// ---------------- Kernel 1b: pool x_ful (temporal — keep in L3 for apply) ----------------
__global__ __launch_bounds__(256, 2) void poolB_kernel(
    const float* __restrict__ xf, float* __restrict__ nodes)
{
    const int row  = blockIdx.x * 4 + (threadIdx.x >> 6);  // 0..8191
    const int lane = threadIdx.x & 63;
    const f4* src = (const f4*)(xf + (size_t)row * 4096);

    f4 v[16];
#pragma unroll
    for (int j = 0; j < 16; ++j) v[j] = src[lane + 64 * j];
    f4 a0 = v[0] + v[1], a1 = v[2] + v[3], a2 = v[4] + v[5], a3 = v[6] + v[7];
    f4 a4 = v[8] + v[9], a5 = v[10] + v[11], a6 = v[12] + v[13], a7 = v[14] + v[15];
    f4 acc = ((a0 + a1) + (a2 + a3)) + ((a4 + a5) + (a6 + a7));

    float s = acc.x + acc.y + acc.z + acc.w;
#pragma unroll
    for (int off = 32; off; off >>= 1) s += __shfl_down(s, off, 64);
    if (lane == 0) {
        const int b = row >> 8, c = row & 255;
        nodes[(size_t)b * 1024 + 1 * CCH + c] = s * (1.f / 4096.f);
    }
}

// ---------------- Kernel 2: 2x (GATConv + residual + LN + ReLU), output gate ----------------
// grid: 32 blocks (batch), 512 threads: c = t&255, kh = t>>8 splits K in half.
// acc[4][4] (head j x node n) stays in registers; halves combine via LDS once.
__global__ __launch_bounds__(512) void gat_kernel(
    const float* __restrict__ nodes, const float* __restrict__ tok,
    float* __restrict__ scale,
    const float* __restrict__ W0, const float* __restrict__ as0,
    const float* __restrict__ ad0, const float* __restrict__ b0,
    const float* __restrict__ g0, const float* __restrict__ be0,
    const float* __restrict__ W1, const float* __restrict__ as1,
    const float* __restrict__ ad1, const float* __restrict__ b1,
    const float* __restrict__ g1, const float* __restrict__ be1)
{
    const int t = threadIdx.x;          // 0..511
    const int b = blockIdx.x;
    const int c = t & 255, kh = t >> 8;
    const int lane = t & 63, wv = t >> 6;   // wv 0..7

    __shared__ float gl[4][CCH];            // node features (layer input)
    __shared__ float xpart[4][4][CCH];      // half-1 GEMM partials [j][n][c]
    __shared__ float redl[4][32];           // per-wave logits partials (waves 0-3)
    __shared__ float esed[32];              // es[n*4+h], ed at +16
    __shared__ float alpha_s[4][4][4];      // [dst][head][src-slot]
    __shared__ float red2[4][8];            // per-wave LN partials
    __shared__ float mu_s[4], rstd_s[4];

    if (t < 256) {
        gl[0][c] = tok[c];
        gl[1][c] = nodes[(size_t)b * 1024 + 256 + c];
        gl[2][c] = nodes[(size_t)b * 1024 + 512 + c];
        gl[3][c] = nodes[(size_t)b * 1024 + 768 + c];
    }
    __syncthreads();

    for (int layer = 0; layer < 2; ++layer) {
        const float* W  = layer ? W1  : W0;
        const float* As = layer ? as1 : as0;
        const float* Ad = layer ? ad1 : ad0;
        const float* Bi = layer ? b1  : b0;
        const float* Ga = layer ? g1  : g0;
        const float* Be = layer ? be1 : be0;

        // ---- xp = x @ W : this thread's K-half, 8-deep register staging
        float acc[4][4];
#pragma unroll
        for (int j = 0; j < 4; ++j)
#pragma unroll
            for (int n = 0; n < 4; ++n) acc[j][n] = 0.f;

        const float* Wp = W + c;
        const int kbase = kh * 128;
        for (int k0 = 0; k0 < 128; k0 += 8) {
            float wr[8][4];
#pragma unroll
            for (int u = 0; u < 8; ++u)
#pragma unroll
                for (int j = 0; j < 4; ++j)
                    wr[u][j] = Wp[(size_t)(kbase + k0 + u) * 1024 + j * 256];
#pragma unroll
            for (int u = 0; u < 8; ++u) {
                const int k = kbase + k0 + u;
                float g0v = gl[0][k], g1v = gl[1][k];
                float g2v = gl[2][k], g3v = gl[3][k];
#pragma unroll
                for (int j = 0; j < 4; ++j) {
                    float w = wr[u][j];
                    acc[j][0] += g0v * w;
                    acc[j][1] += g1v * w;
                    acc[j][2] += g2v * w;
                    acc[j][3] += g3v * w;
                }
            }
        }
        if (kh == 1) {
#pragma unroll
            for (int j = 0; j < 4; ++j)
#pragma unroll
                for (int n = 0; n < 4; ++n) xpart[j][n][c] = acc[j][n];
        }
        __syncthreads();

        float gv[4];
        if (kh == 0) {
#pragma unroll
            for (int j = 0; j < 4; ++j)
#pragma unroll
                for (int n = 0; n < 4; ++n) acc[j][n] += xpart[j][n][c];

            // ---- attention logits: 32 simultaneous shuffle-reductions over c
            float asr[4], adr[4];
#pragma unroll
            for (int j = 0; j < 4; ++j) { asr[j] = As[j * 256 + c]; adr[j] = Ad[j * 256 + c]; }
            float rv[32];
#pragma unroll
            for (int n = 0; n < 4; ++n)
#pragma unroll
                for (int j = 0; j < 4; ++j) {
                    rv[n * 4 + j]      = acc[j][n] * asr[j];
                    rv[16 + n * 4 + j] = acc[j][n] * adr[j];
                }
#pragma unroll
            for (int i = 0; i < 32; ++i)
#pragma unroll
                for (int off = 32; off; off >>= 1)
                    rv[i] += __shfl_down(rv[i], off, 64);
            if (lane == 0) {
#pragma unroll
                for (int i = 0; i < 32; ++i) redl[wv][i] = rv[i];
            }
        }
        __syncthreads();
        if (t < 32) esed[t] = redl[0][t] + redl[1][t] + redl[2][t] + redl[3][t];
        __syncthreads();

        // ---- per-destination segment softmax (16 threads: d*4+h)
        if (t < 16) {
            const int d = t >> 2, hh = t & 3;
            const int cnt[4]     = {4, 3, 3, 3};
            const int srcs[4][4] = {{1,2,3,0},{2,3,1,0},{1,3,2,0},{1,2,3,0}};
            float v[4];
            float m = -1e30f;
            const int n = cnt[d];
            for (int s = 0; s < n; ++s) {
                float e = esed[srcs[d][s] * 4 + hh] + esed[16 + d * 4 + hh];
                e = (e >= 0.f) ? e : 0.2f * e;         // leaky_relu 0.2
                v[s] = e; m = fmaxf(m, e);
            }
            float den = 0.f;
            for (int s = 0; s < n; ++s) { v[s] = expf(v[s] - m); den += v[s]; }
            float inv = 1.f / den;
            for (int s = 0; s < n; ++s) alpha_s[d][hh][s] = v[s] * inv;
            for (int s = n; s < 4; ++s) alpha_s[d][hh][s] = 0.f;
        }
        __syncthreads();

        if (kh == 0) {
            // ---- aggregate + head mean + bias + residual (registers)
            const int srcs2[4][4] = {{1,2,3,0},{2,3,1,0},{1,3,2,0},{1,2,3,0}};
            float bi = Bi[c];
#pragma unroll
            for (int d = 0; d < 4; ++d) {
                float sum = 0.f;
#pragma unroll
                for (int j = 0; j < 4; ++j) {
                    float mj = 0.f;
#pragma unroll
                    for (int s = 0; s < 4; ++s)
                        mj += alpha_s[d][j][s] * acc[j][srcs2[d][s]];
                    sum += mj;
                }
                gv[d] = 0.25f * sum + bi + gl[d][c];
            }

            // ---- LayerNorm: 8 simultaneous shuffle-reductions
            float rv2[8];
#pragma unroll
            for (int d = 0; d < 4; ++d) { rv2[d * 2] = gv[d]; rv2[d * 2 + 1] = gv[d] * gv[d]; }
#pragma unroll
            for (int i = 0; i < 8; ++i)
#pragma unroll
                for (int off = 32; off; off >>= 1)
                    rv2[i] += __shfl_down(rv2[i], off, 64);
            if (lane == 0) {
#pragma unroll
                for (int i = 0; i < 8; ++i) red2[wv][i] = rv2[i];
            }
        }
        __syncthreads();
        if (t < 4) {
            float s = red2[0][t*2]   + red2[1][t*2]   + red2[2][t*2]   + red2[3][t*2];
            float q = red2[0][t*2+1] + red2[1][t*2+1] + red2[2][t*2+1] + red2[3][t*2+1];
            float mu  = s * (1.f / 256.f);
            float var = q * (1.f / 256.f) - mu * mu;
            mu_s[t]   = mu;
            rstd_s[t] = rsqrtf(var + 1e-5f);
        }
        __syncthreads();
        if (kh == 0) {
            float ga = Ga[c], be = Be[c];
#pragma unroll
            for (int d = 0; d < 4; ++d) {
                float y = (gv[d] - mu_s[d]) * rstd_s[d] * ga + be;
                gl[d][c] = fmaxf(y, 0.f);
            }
        }
        __syncthreads();
    }

    // ---- output gate from token node: scale = 1 + sigmoid(g[b,0,c])
    if (t < 256) {
        float x = gl[0][c];
        scale[(size_t)b * CCH + c] = 1.f + 1.f / (1.f + expf(-x));
    }
}

// ---------------- Kernel 3: out = x_ful * (1 + sigmoid), nontemporal store ----------------
__global__ __launch_bounds__(256) void apply_kernel(
    const float* __restrict__ xf, const float* __restrict__ scale,
    float* __restrict__ out, int total4)
{
    int idx = blockIdx.x * 256 + threadIdx.x;
    const int stride = gridDim.x * 256;
    const f4* in4 = (const f4*)xf;
    f4* out4 = (f4*)out;
    for (; idx < total4; idx += stride) {
        f4 v = in4[idx];
        const float s = scale[idx >> 10];          // 1024 float4 per (b,c) row
        f4 o = v * s;
        __builtin_nontemporal_store(o, out4 + idx);
    }
}

extern "C" void kernel_launch(void* const* d_in, const int* in_sizes, int n_in,
                              void* d_out, int out_size, void* d_ws, size_t ws_size,
                              hipStream_t stream) {
    const float* x_ful = (const float*)d_in[0];
    const float* rgb   = (const float*)d_in[1];
    const float* dep   = (const float*)d_in[2];
    const float* tok   = (const float*)d_in[3];
    const float* W0  = (const float*)d_in[4];
    const float* as0 = (const float*)d_in[5];
    const float* ad0 = (const float*)d_in[6];
    const float* b0  = (const float*)d_in[7];
    const float* g0  = (const float*)d_in[8];
    const float* be0 = (const float*)d_in[9];
    const float* W1  = (const float*)d_in[10];
    const float* as1 = (const float*)d_in[11];
    const float* ad1 = (const float*)d_in[12];
    const float* b1  = (const float*)d_in[13];
    const float* g1  = (const float*)d_in[14];
    const float* be1 = (const float*)d_in[15];

    float* nodes = (float*)d_ws;                          // [32][4][256] = 128 KB
    float* scale = (float*)((char*)d_ws + 32 * 4 * CCH * sizeof(float)); // [32][256]
    float* out   = (float*)d_out;

    // rgb+dep first (nontemporal), x_ful last (temporal -> L3-resident for apply)
    poolA_kernel<<<4096, 256, 0, stream>>>(rgb, dep, nodes);
    poolB_kernel<<<2048, 256, 0, stream>>>(x_ful, nodes);
    gat_kernel<<<32, 512, 0, stream>>>(nodes, tok, scale,
                                       W0, as0, ad0, b0, g0, be0,
                                       W1, as1, ad1, b1, g1, be1);
    const int total4 = 32 * CCH * 64 * 64 / 4;            // 8,388,608 float4
    apply_kernel<<<2048, 256, 0, stream>>>(x_ful, scale, out, total4);
}

// Round 6
// 164.847 us; speedup vs baseline: 1.1944x; 1.0251x over previous
//
#include <hip/hip_runtime.h>
#include <hip/hip_bf16.h>

#define CCH 256
#define HEADS 4

typedef float f4 __attribute__((ext_vector_type(4)));

// ---------------- Kernel 1a: pool rgb + dep (nontemporal) ----------------
// wave-per-row: 64 lanes x 16 float4 = 4096 floats; 16-deep register burst.
__global__ __launch_bounds__(256, 2) void poolA_kernel(
    const float* __restrict__ rgb, const float* __restrict__ dep,
    float* __restrict__ nodes /* [32][4][256] */)
{
    const int rw   = blockIdx.x * 4 + (threadIdx.x >> 6);  // 0..16383
    const int lane = threadIdx.x & 63;
    const int tensor = rw >> 13;              // 0 = rgb, 1 = dep
    const int row    = rw & 8191;             // b*256 + c
    const f4* src = (const f4*)((tensor ? dep : rgb) + (size_t)row * 4096);

    f4 v[16];
#pragma unroll
    for (int j = 0; j < 16; ++j) v[j] = __builtin_nontemporal_load(src + lane + 64 * j);
    f4 a0 = v[0] + v[1], a1 = v[2] + v[3], a2 = v[4] + v[5], a3 = v[6] + v[7];
    f4 a4 = v[8] + v[9], a5 = v[10] + v[11], a6 = v[12] + v[13], a7 = v[14] + v[15];
    f4 acc = ((a0 + a1) + (a2 + a3)) + ((a4 + a5) + (a6 + a7));

    float s = acc.x + acc.y + acc.z + acc.w;
#pragma unroll
    for (int off = 32; off; off >>= 1) s += __shfl_down(s, off, 64);
    if (lane == 0) {
        const int b = row >> 8, c = row & 255;
        nodes[(size_t)b * 1024 + (2 + tensor) * CCH + c] = s * (1.f / 4096.f);
    }
}

// ---------------- Kernel 1b: pool x_ful (temporal — keep in L3 for apply) ----------------
__global__ __launch_bounds__(256, 2) void poolB_kernel(
    const float* __restrict__ xf, float* __restrict__ nodes)
{
    const int row  = blockIdx.x * 4 + (threadIdx.x >> 6);  // 0..8191
    const int lane = threadIdx.x & 63;
    const f4* src = (const f4*)(xf + (size_t)row * 4096);

    f4 v[16];
#pragma unroll
    for (int j = 0; j < 16; ++j) v[j] = src[lane + 64 * j];
    f4 a0 = v[0] + v[1], a1 = v[2] + v[3], a2 = v[4] + v[5], a3 = v[6] + v[7];
    f4 a4 = v[8] + v[9], a5 = v[10] + v[11], a6 = v[12] + v[13], a7 = v[14] + v[15];
    f4 acc = ((a0 + a1) + (a2 + a3)) + ((a4 + a5) + (a6 + a7));

    float s = acc.x + acc.y + acc.z + acc.w;
#pragma unroll
    for (int off = 32; off; off >>= 1) s += __shfl_down(s, off, 64);
    if (lane == 0) {
        const int b = row >> 8, c = row & 255;
        nodes[(size_t)b * 1024 + 1 * CCH + c] = s * (1.f / 4096.f);
    }
}

// ---------------- Kernel 2: 2x (GATConv + residual + LN + ReLU), output gate ----------------
// grid: 32 blocks (batch), 512 threads: c = t&255, kh = t>>8 splits K in half.
// launch_bounds(512,2): VGPR cap 256 so the 64-float W staging stays in registers
// (at the default cap of 64 VGPR the compiler re-rolls the staging and the W
// loads serialize at ~200+ cyc each -> the 100 us R5 kernel).
__global__ __launch_bounds__(512, 2) void gat_kernel(
    const float* __restrict__ nodes, const float* __restrict__ tok,
    float* __restrict__ scale,
    const float* __restrict__ W0, const float* __restrict__ as0,
    const float* __restrict__ ad0, const float* __restrict__ b0,
    const float* __restrict__ g0, const float* __restrict__ be0,
    const float* __restrict__ W1, const float* __restrict__ as1,
    const float* __restrict__ ad1, const float* __restrict__ b1,
    const float* __restrict__ g1, const float* __restrict__ be1)
{
    const int t = threadIdx.x;          // 0..511
    const int b = blockIdx.x;
    const int c = t & 255, kh = t >> 8;
    const int lane = t & 63, wv = t >> 6;   // wv 0..7

    __shared__ float gl[4][CCH];            // node features (layer input)
    __shared__ float xpart[4][4][CCH];      // half-1 GEMM partials [j][n][c]
    __shared__ float redl[4][32];           // per-wave logits partials (waves 0-3)
    __shared__ float esed[32];              // es[n*4+h], ed at +16
    __shared__ float alpha_s[4][4][4];      // [dst][head][src-slot]
    __shared__ float red2[4][8];            // per-wave LN partials
    __shared__ float mu_s[4], rstd_s[4];

    if (t < 256) {
        gl[0][c] = tok[c];
        gl[1][c] = nodes[(size_t)b * 1024 + 256 + c];
        gl[2][c] = nodes[(size_t)b * 1024 + 512 + c];
        gl[3][c] = nodes[(size_t)b * 1024 + 768 + c];
    }
    __syncthreads();

    for (int layer = 0; layer < 2; ++layer) {
        const float* W  = layer ? W1  : W0;
        const float* As = layer ? as1 : as0;
        const float* Ad = layer ? ad1 : ad0;
        const float* Bi = layer ? b1  : b0;
        const float* Ga = layer ? g1  : g0;
        const float* Be = layer ? be1 : be0;

        // ---- xp = x @ W : this thread's K-half, 16-deep register staging
        float acc[4][4];
#pragma unroll
        for (int j = 0; j < 4; ++j)
#pragma unroll
            for (int n = 0; n < 4; ++n) acc[j][n] = 0.f;

        const float* Wp = W + c;
        const int kbase = kh * 128;
        for (int k0 = 0; k0 < 128; k0 += 16) {
            float wr[16][4];
#pragma unroll
            for (int u = 0; u < 16; ++u)
#pragma unroll
                for (int j = 0; j < 4; ++j)
                    wr[u][j] = Wp[(size_t)(kbase + k0 + u) * 1024 + j * 256];
#pragma unroll
            for (int u = 0; u < 16; ++u) {
                const int k = kbase + k0 + u;
                float g0v = gl[0][k], g1v = gl[1][k];
                float g2v = gl[2][k], g3v = gl[3][k];
#pragma unroll
                for (int j = 0; j < 4; ++j) {
                    float w = wr[u][j];
                    acc[j][0] += g0v * w;
                    acc[j][1] += g1v * w;
                    acc[j][2] += g2v * w;
                    acc[j][3] += g3v * w;
                }
            }
        }
        if (kh == 1) {
#pragma unroll
            for (int j = 0; j < 4; ++j)
#pragma unroll
                for (int n = 0; n < 4; ++n) xpart[j][n][c] = acc[j][n];
        }
        __syncthreads();

        float gv[4];
        if (kh == 0) {
#pragma unroll
            for (int j = 0; j < 4; ++j)
#pragma unroll
                for (int n = 0; n < 4; ++n) acc[j][n] += xpart[j][n][c];

            // ---- attention logits: 32 simultaneous shuffle-reductions over c
            float asr[4], adr[4];
#pragma unroll
            for (int j = 0; j < 4; ++j) { asr[j] = As[j * 256 + c]; adr[j] = Ad[j * 256 + c]; }
            float rv[32];
#pragma unroll
            for (int n = 0; n < 4; ++n)
#pragma unroll
                for (int j = 0; j < 4; ++j) {
                    rv[n * 4 + j]      = acc[j][n] * asr[j];
                    rv[16 + n * 4 + j] = acc[j][n] * adr[j];
                }
#pragma unroll
            for (int i = 0; i < 32; ++i)
#pragma unroll
                for (int off = 32; off; off >>= 1)
                    rv[i] += __shfl_down(rv[i], off, 64);
            if (lane == 0) {
#pragma unroll
                for (int i = 0; i < 32; ++i) redl[wv][i] = rv[i];
            }
        }
        __syncthreads();
        if (t < 32) esed[t] = redl[0][t] + redl[1][t] + redl[2][t] + redl[3][t];
        __syncthreads();

        // ---- per-destination segment softmax (16 threads: d*4+h)
        if (t < 16) {
            const int d = t >> 2, hh = t & 3;
            const int cnt[4]     = {4, 3, 3, 3};
            const int srcs[4][4] = {{1,2,3,0},{2,3,1,0},{1,3,2,0},{1,2,3,0}};
            float v[4];
            float m = -1e30f;
            const int n = cnt[d];
            for (int s = 0; s < n; ++s) {
                float e = esed[srcs[d][s] * 4 + hh] + esed[16 + d * 4 + hh];
                e = (e >= 0.f) ? e : 0.2f * e;         // leaky_relu 0.2
                v[s] = e; m = fmaxf(m, e);
            }
            float den = 0.f;
            for (int s = 0; s < n; ++s) { v[s] = expf(v[s] - m); den += v[s]; }
            float inv = 1.f / den;
            for (int s = 0; s < n; ++s) alpha_s[d][hh][s] = v[s] * inv;
            for (int s = n; s < 4; ++s) alpha_s[d][hh][s] = 0.f;
        }
        __syncthreads();

        if (kh == 0) {
            // ---- aggregate + head mean + bias + residual (registers)
            const int srcs2[4][4] = {{1,2,3,0},{2,3,1,0},{1,3,2,0},{1,2,3,0}};
            float bi = Bi[c];
#pragma unroll
            for (int d = 0; d < 4; ++d) {
                float sum = 0.f;
#pragma unroll
                for (int j = 0; j < 4; ++j) {
                    float mj = 0.f;
#pragma unroll
                    for (int s = 0; s < 4; ++s)
                        mj += alpha_s[d][j][s] * acc[j][srcs2[d][s]];
                    sum += mj;
                }
                gv[d] = 0.25f * sum + bi + gl[d][c];
            }

            // ---- LayerNorm: 8 simultaneous shuffle-reductions
            float rv2[8];
#pragma unroll
            for (int d = 0; d < 4; ++d) { rv2[d * 2] = gv[d]; rv2[d * 2 + 1] = gv[d] * gv[d]; }
#pragma unroll
            for (int i = 0; i < 8; ++i)
#pragma unroll
                for (int off = 32; off; off >>= 1)
                    rv2[i] += __shfl_down(rv2[i], off, 64);
            if (lane == 0) {
#pragma unroll
                for (int i = 0; i < 8; ++i) red2[wv][i] = rv2[i];
            }
        }
        __syncthreads();
        if (t < 4) {
            float s = red2[0][t*2]   + red2[1][t*2]   + red2[2][t*2]   + red2[3][t*2];
            float q = red2[0][t*2+1] + red2[1][t*2+1] + red2[2][t*2+1] + red2[3][t*2+1];
            float mu  = s * (1.f / 256.f);
            float var = q * (1.f / 256.f) - mu * mu;
            mu_s[t]   = mu;
            rstd_s[t] = rsqrtf(var + 1e-5f);
        }
        __syncthreads();
        if (kh == 0) {
            float ga = Ga[c], be = Be[c];
#pragma unroll
            for (int d = 0; d < 4; ++d) {
                float y = (gv[d] - mu_s[d]) * rstd_s[d] * ga + be;
                gl[d][c] = fmaxf(y, 0.f);
            }
        }
        __syncthreads();
    }

    // ---- output gate from token node: scale = 1 + sigmoid(g[b,0,c])
    if (t < 256) {
        float x = gl[0][c];
        scale[(size_t)b * CCH + c] = 1.f + 1.f / (1.f + expf(-x));
    }
}

// ---------------- Kernel 3: out = x_ful * (1 + sigmoid), nontemporal store ----------------
__global__ __launch_bounds__(256) void apply_kernel(
    const float* __restrict__ xf, const float* __restrict__ scale,
    float* __restrict__ out, int total4)
{
    int idx = blockIdx.x * 256 + threadIdx.x;
    const int stride = gridDim.x * 256;
    const f4* in4 = (const f4*)xf;
    f4* out4 = (f4*)out;
    for (; idx < total4; idx += stride) {
        f4 v = in4[idx];
        const float s = scale[idx >> 10];          // 1024 float4 per (b,c) row
        f4 o = v * s;
        __builtin_nontemporal_store(o, out4 + idx);
    }
}

extern "C" void kernel_launch(void* const* d_in, const int* in_sizes, int n_in,
                              void* d_out, int out_size, void* d_ws, size_t ws_size,
                              hipStream_t stream) {
    const float* x_ful = (const float*)d_in[0];
    const float* rgb   = (const float*)d_in[1];
    const float* dep   = (const float*)d_in[2];
    const float* tok   = (const float*)d_in[3];
    const float* W0  = (const float*)d_in[4];
    const float* as0 = (const float*)d_in[5];
    const float* ad0 = (const float*)d_in[6];
    const float* b0  = (const float*)d_in[7];
    const float* g0  = (const float*)d_in[8];
    const float* be0 = (const float*)d_in[9];
    const float* W1  = (const float*)d_in[10];
    const float* as1 = (const float*)d_in[11];
    const float* ad1 = (const float*)d_in[12];
    const float* b1  = (const float*)d_in[13];
    const float* g1  = (const float*)d_in[14];
    const float* be1 = (const float*)d_in[15];

    float* nodes = (float*)d_ws;                          // [32][4][256] = 128 KB
    float* scale = (float*)((char*)d_ws + 32 * 4 * CCH * sizeof(float)); // [32][256]
    float* out   = (float*)d_out;

    // rgb+dep first (nontemporal), x_ful last (temporal -> L3-resident for apply)
    poolA_kernel<<<4096, 256, 0, stream>>>(rgb, dep, nodes);
    poolB_kernel<<<2048, 256, 0, stream>>>(x_ful, nodes);
    gat_kernel<<<32, 512, 0, stream>>>(nodes, tok, scale,
                                       W0, as0, ad0, b0, g0, be0,
                                       W1, as1, ad1, b1, g1, be1);
    const int total4 = 32 * CCH * 64 * 64 / 4;            // 8,388,608 float4
    apply_kernel<<<2048, 256, 0, stream>>>(x_ful, scale, out, total4);
}

// Round 7
// 142.369 us; speedup vs baseline: 1.3829x; 1.1579x over previous
//
#include <hip/hip_runtime.h>
#include <hip/hip_bf16.h>

#define CCH 256

typedef float f4 __attribute__((ext_vector_type(4)));

// ---------------- Kernel 1a: pool rgb + dep (nontemporal) ----------------
__global__ __launch_bounds__(256, 2) void poolA_kernel(
    const float* __restrict__ rgb, const float* __restrict__ dep,
    float* __restrict__ nodes /* [32][4][256] */)
{
    const int rw   = blockIdx.x * 4 + (threadIdx.x >> 6);  // 0..16383
    const int lane = threadIdx.x & 63;
    const int tensor = rw >> 13;              // 0 = rgb, 1 = dep
    const int row    = rw & 8191;             // b*256 + c
    const f4* src = (const f4*)((tensor ? dep : rgb) + (size_t)row * 4096);

    f4 v[16];
#pragma unroll
    for (int j = 0; j < 16; ++j) v[j] = __builtin_nontemporal_load(src + lane + 64 * j);
    f4 a0 = v[0] + v[1], a1 = v[2] + v[3], a2 = v[4] + v[5], a3 = v[6] + v[7];
    f4 a4 = v[8] + v[9], a5 = v[10] + v[11], a6 = v[12] + v[13], a7 = v[14] + v[15];
    f4 acc = ((a0 + a1) + (a2 + a3)) + ((a4 + a5) + (a6 + a7));

    float s = acc.x + acc.y + acc.z + acc.w;
#pragma unroll
    for (int off = 32; off; off >>= 1) s += __shfl_down(s, off, 64);
    if (lane == 0) {
        const int b = row >> 8, c = row & 255;
        nodes[(size_t)b * 1024 + (2 + tensor) * CCH + c] = s * (1.f / 4096.f);
    }
}

// ---------------- Kernel 1b: pool x_ful (temporal — keep in L3 for apply) ----------------
__global__ __launch_bounds__(256, 2) void poolB_kernel(
    const float* __restrict__ xf, float* __restrict__ nodes)
{
    const int row  = blockIdx.x * 4 + (threadIdx.x >> 6);  // 0..8191
    const int lane = threadIdx.x & 63;
    const f4* src = (const f4*)(xf + (size_t)row * 4096);

    f4 v[16];
#pragma unroll
    for (int j = 0; j < 16; ++j) v[j] = src[lane + 64 * j];
    f4 a0 = v[0] + v[1], a1 = v[2] + v[3], a2 = v[4] + v[5], a3 = v[6] + v[7];
    f4 a4 = v[8] + v[9], a5 = v[10] + v[11], a6 = v[12] + v[13], a7 = v[14] + v[15];
    f4 acc = ((a0 + a1) + (a2 + a3)) + ((a4 + a5) + (a6 + a7));

    float s = acc.x + acc.y + acc.z + acc.w;
#pragma unroll
    for (int off = 32; off; off >>= 1) s += __shfl_down(s, off, 64);
    if (lane == 0) {
        const int b = row >> 8, c = row & 255;
        nodes[(size_t)b * 1024 + 1 * CCH + c] = s * (1.f / 4096.f);
    }
}

// ======== GAT helpers: per-(batch,head) GEMM + logits + softmax + aggregate ========
// Fixed topology tables (PyG GATConv with self loops on the 4-node graph):
//   dst 0 <- {1,2,3,0}; dst 1 <- {2,3,1}; dst 2 <- {1,3,2}; dst 3 <- {1,2,3}
__device__ __forceinline__ void gat_head_core(
    const float X[4][CCH], const float* __restrict__ W,
    const float* __restrict__ As, const float* __restrict__ Ad,
    int h, int c, int lane, int wv,
    float redl[4][8], float esed[8], float alpha_s[4][4],
    float* __restrict__ msg_out /* + b*4096 + h*1024 + c */)
{
    // GEMM: acc[n] = sum_k X[n][k] * W[k][h*256+c], 16-deep register staging
    float acc[4] = {0.f, 0.f, 0.f, 0.f};
    const float* Wp = W + h * 256 + c;
    for (int k0 = 0; k0 < 256; k0 += 16) {
        float wr[16];
#pragma unroll
        for (int u = 0; u < 16; ++u) wr[u] = Wp[(k0 + u) * 1024];
#pragma unroll
        for (int u = 0; u < 16; ++u) {
            float w = wr[u];
            acc[0] += X[0][k0 + u] * w;
            acc[1] += X[1][k0 + u] * w;
            acc[2] += X[2][k0 + u] * w;
            acc[3] += X[3][k0 + u] * w;
        }
    }

    // logits: 8 simultaneous reductions over c (4 nodes x {src,dst})
    const float av = As[h * 256 + c], dv = Ad[h * 256 + c];
    float rv[8];
#pragma unroll
    for (int n = 0; n < 4; ++n) { rv[n] = acc[n] * av; rv[4 + n] = acc[n] * dv; }
#pragma unroll
    for (int i = 0; i < 8; ++i)
#pragma unroll
        for (int off = 32; off; off >>= 1)
            rv[i] += __shfl_down(rv[i], off, 64);
    if (lane == 0) {
#pragma unroll
        for (int i = 0; i < 8; ++i) redl[wv][i] = rv[i];
    }
    __syncthreads();
    if (c < 8) esed[c] = redl[0][c] + redl[1][c] + redl[2][c] + redl[3][c];
    __syncthreads();

    // segment softmax per destination (4 threads, one per dst)
    if (c < 4) {
        const int cnt[4]     = {4, 3, 3, 3};
        const int srcs[4][4] = {{1,2,3,0},{2,3,1,0},{1,3,2,0},{1,2,3,0}};
        const int d = c, n = cnt[d];
        float v[4], m = -1e30f;
        for (int s = 0; s < n; ++s) {
            float e = esed[srcs[d][s]] + esed[4 + d];
            e = (e >= 0.f) ? e : 0.2f * e;        // leaky_relu 0.2
            v[s] = e; m = fmaxf(m, e);
        }
        float den = 0.f;
        for (int s = 0; s < n; ++s) { v[s] = __expf(v[s] - m); den += v[s]; }
        float inv = 1.f / den;
        for (int s = 0; s < n; ++s) alpha_s[d][s] = v[s] * inv;
        for (int s = n; s < 4; ++s) alpha_s[d][s] = 0.f;
    }
    __syncthreads();

    // aggregate per dst and write per-head message
    const int srcs2[4][4] = {{1,2,3,0},{2,3,1,0},{1,3,2,0},{1,2,3,0}};
#pragma unroll
    for (int d = 0; d < 4; ++d) {
        float s = 0.f;
#pragma unroll
        for (int sl = 0; sl < 4; ++sl)
            s += alpha_s[d][sl] * acc[srcs2[d][sl]];
        msg_out[d * 256] = s;
    }
}

// ---------------- Kernel 2a: layer-0 per-head GAT ----------------
// grid: 128 blocks = b*4+h, 256 threads = channel c.
__global__ __launch_bounds__(256) void gemmA_kernel(
    const float* __restrict__ nodes, const float* __restrict__ tok,
    const float* __restrict__ W0, const float* __restrict__ as0,
    const float* __restrict__ ad0, float* __restrict__ msg1)
{
    const int bid = blockIdx.x, b = bid >> 2, h = bid & 3;
    const int c = threadIdx.x, lane = c & 63, wv = c >> 6;

    __shared__ float X[4][CCH];
    __shared__ float redl[4][8];
    __shared__ float esed[8];
    __shared__ float alpha_s[4][4];

    X[0][c] = tok[c];
    X[1][c] = nodes[b * 1024 + 256 + c];
    X[2][c] = nodes[b * 1024 + 512 + c];
    X[3][c] = nodes[b * 1024 + 768 + c];
    __syncthreads();

    gat_head_core(X, W0, as0, ad0, h, c, lane, wv, redl, esed, alpha_s,
                  msg1 + b * 4096 + h * 1024 + c);
}

// ---------------- Kernel 2b: recompute gl1 (mean+bias+residual+LN+ReLU), layer-1 per-head GAT ----------------
__global__ __launch_bounds__(256) void gemmB_kernel(
    const float* __restrict__ nodes, const float* __restrict__ tok,
    const float* __restrict__ msg1,
    const float* __restrict__ b0, const float* __restrict__ g0,
    const float* __restrict__ be0,
    const float* __restrict__ W1, const float* __restrict__ as1,
    const float* __restrict__ ad1, float* __restrict__ msg2)
{
    const int bid = blockIdx.x, b = bid >> 2, h = bid & 3;
    const int c = threadIdx.x, lane = c & 63, wv = c >> 6;

    __shared__ float X[4][CCH];          // gl1
    __shared__ float redl[4][8];
    __shared__ float esed[8];
    __shared__ float alpha_s[4][4];
    __shared__ float mu_s[4], rstd_s[4];

    // gl1 = relu(LN(0.25*sum_h msg1 + b0 + gl0))  — redundant across the 4 h-blocks (cheap)
    const float* m1 = msg1 + b * 4096 + c;   // [h][d] stride: h*1024 + d*256
    float gv[4];
#pragma unroll
    for (int d = 0; d < 4; ++d) {
        float s = m1[d * 256] + m1[1024 + d * 256] + m1[2048 + d * 256] + m1[3072 + d * 256];
        float x0 = (d == 0) ? tok[c] : nodes[b * 1024 + d * 256 + c];
        gv[d] = 0.25f * s + b0[c] + x0;
    }
    float rv[8];
#pragma unroll
    for (int d = 0; d < 4; ++d) { rv[d * 2] = gv[d]; rv[d * 2 + 1] = gv[d] * gv[d]; }
#pragma unroll
    for (int i = 0; i < 8; ++i)
#pragma unroll
        for (int off = 32; off; off >>= 1)
            rv[i] += __shfl_down(rv[i], off, 64);
    if (lane == 0) {
#pragma unroll
        for (int i = 0; i < 8; ++i) redl[wv][i] = rv[i];
    }
    __syncthreads();
    if (c < 4) {
        float s = redl[0][c*2]   + redl[1][c*2]   + redl[2][c*2]   + redl[3][c*2];
        float q = redl[0][c*2+1] + redl[1][c*2+1] + redl[2][c*2+1] + redl[3][c*2+1];
        float mu  = s * (1.f / 256.f);
        float var = q * (1.f / 256.f) - mu * mu;
        mu_s[c] = mu; rstd_s[c] = rsqrtf(var + 1e-5f);
    }
    __syncthreads();
    float ga = g0[c], be = be0[c];
#pragma unroll
    for (int d = 0; d < 4; ++d)
        X[d][c] = fmaxf((gv[d] - mu_s[d]) * rstd_s[d] * ga + be, 0.f);
    __syncthreads();

    gat_head_core(X, W1, as1, ad1, h, c, lane, wv, redl, esed, alpha_s,
                  msg2 + b * 4096 + h * 1024 + c);
}

// ---------------- Kernel 2c: finish — token-row LN chain -> scale ----------------
// grid: 32 blocks (batch), 256 threads.
__global__ __launch_bounds__(256) void finish_kernel(
    const float* __restrict__ tok,
    const float* __restrict__ msg1, const float* __restrict__ msg2,
    const float* __restrict__ b0, const float* __restrict__ g0,
    const float* __restrict__ be0,
    const float* __restrict__ b1, const float* __restrict__ g1,
    const float* __restrict__ be1,
    float* __restrict__ scale)
{
    const int b = blockIdx.x, c = threadIdx.x;
    const int lane = c & 63, wv = c >> 6;
    __shared__ float redl[4][2];
    __shared__ float mrs[2];

    // layer-0 token row: gv1 = 0.25*sum_h msg1[b][h][0][c] + b0 + tok
    const float* m1 = msg1 + b * 4096 + c;
    float gv1 = 0.25f * (m1[0] + m1[1024] + m1[2048] + m1[3072]) + b0[c] + tok[c];
    {
        float s = gv1, q = gv1 * gv1;
#pragma unroll
        for (int off = 32; off; off >>= 1) { s += __shfl_down(s, off, 64); q += __shfl_down(q, off, 64); }
        if (lane == 0) { redl[wv][0] = s; redl[wv][1] = q; }
        __syncthreads();
        if (c == 0) {
            float ss = redl[0][0] + redl[1][0] + redl[2][0] + redl[3][0];
            float qq = redl[0][1] + redl[1][1] + redl[2][1] + redl[3][1];
            float mu = ss * (1.f / 256.f);
            mrs[0] = mu; mrs[1] = rsqrtf(qq * (1.f / 256.f) - mu * mu + 1e-5f);
        }
        __syncthreads();
    }
    float y1 = fmaxf((gv1 - mrs[0]) * mrs[1] * g0[c] + be0[c], 0.f);
    __syncthreads();

    // layer-1 token row
    const float* m2 = msg2 + b * 4096 + c;
    float gv2 = 0.25f * (m2[0] + m2[1024] + m2[2048] + m2[3072]) + b1[c] + y1;
    {
        float s = gv2, q = gv2 * gv2;
#pragma unroll
        for (int off = 32; off; off >>= 1) { s += __shfl_down(s, off, 64); q += __shfl_down(q, off, 64); }
        if (lane == 0) { redl[wv][0] = s; redl[wv][1] = q; }
        __syncthreads();
        if (c == 0) {
            float ss = redl[0][0] + redl[1][0] + redl[2][0] + redl[3][0];
            float qq = redl[0][1] + redl[1][1] + redl[2][1] + redl[3][1];
            float mu = ss * (1.f / 256.f);
            mrs[0] = mu; mrs[1] = rsqrtf(qq * (1.f / 256.f) - mu * mu + 1e-5f);
        }
        __syncthreads();
    }
    float y2 = fmaxf((gv2 - mrs[0]) * mrs[1] * g1[c] + be1[c], 0.f);
    scale[b * CCH + c] = 1.f + 1.f / (1.f + __expf(-y2));
}

// ---------------- Kernel 3: out = x_ful * (1 + sigmoid), nontemporal store ----------------
__global__ __launch_bounds__(256) void apply_kernel(
    const float* __restrict__ xf, const float* __restrict__ scale,
    float* __restrict__ out, int total4)
{
    int idx = blockIdx.x * 256 + threadIdx.x;
    const int stride = gridDim.x * 256;
    const f4* in4 = (const f4*)xf;
    f4* out4 = (f4*)out;
    for (; idx < total4; idx += stride) {
        f4 v = in4[idx];
        const float s = scale[idx >> 10];          // 1024 float4 per (b,c) row
        f4 o = v * s;
        __builtin_nontemporal_store(o, out4 + idx);
    }
}

extern "C" void kernel_launch(void* const* d_in, const int* in_sizes, int n_in,
                              void* d_out, int out_size, void* d_ws, size_t ws_size,
                              hipStream_t stream) {
    const float* x_ful = (const float*)d_in[0];
    const float* rgb   = (const float*)d_in[1];
    const float* dep   = (const float*)d_in[2];
    const float* tok   = (const float*)d_in[3];
    const float* W0  = (const float*)d_in[4];
    const float* as0 = (const float*)d_in[5];
    const float* ad0 = (const float*)d_in[6];
    const float* b0  = (const float*)d_in[7];
    const float* g0  = (const float*)d_in[8];
    const float* be0 = (const float*)d_in[9];
    const float* W1  = (const float*)d_in[10];
    const float* as1 = (const float*)d_in[11];
    const float* ad1 = (const float*)d_in[12];
    const float* b1  = (const float*)d_in[13];
    const float* g1  = (const float*)d_in[14];
    const float* be1 = (const float*)d_in[15];

    float* ws    = (float*)d_ws;
    float* nodes = ws;                 // [32][4][256]   = 32768 floats
    float* scale = ws + 32768;         // [32][256]      =  8192 floats
    float* msg1  = ws + 40960;         // [32][4][4][256]= 131072 floats
    float* msg2  = ws + 172032;        // [32][4][4][256]= 131072 floats
    float* out   = (float*)d_out;

    // rgb+dep first (nontemporal), x_ful last (temporal -> L3-resident for apply)
    poolA_kernel<<<4096, 256, 0, stream>>>(rgb, dep, nodes);
    poolB_kernel<<<2048, 256, 0, stream>>>(x_ful, nodes);
    gemmA_kernel<<<128, 256, 0, stream>>>(nodes, tok, W0, as0, ad0, msg1);
    gemmB_kernel<<<128, 256, 0, stream>>>(nodes, tok, msg1, b0, g0, be0,
                                          W1, as1, ad1, msg2);
    finish_kernel<<<32, 256, 0, stream>>>(tok, msg1, msg2,
                                          b0, g0, be0, b1, g1, be1, scale);
    const int total4 = 32 * CCH * 64 * 64 / 4;            // 8,388,608 float4
    apply_kernel<<<2048, 256, 0, stream>>>(x_ful, scale, out, total4);
}